// Round 1
// baseline (349.637 us; speedup 1.0000x reference)
//
#include <hip/hip_runtime.h>
#include <math.h>

typedef _Float16 f16;
typedef _Float16 f16x8 __attribute__((ext_vector_type(8)));
typedef _Float16 f16x4 __attribute__((ext_vector_type(4)));
typedef float f32x4 __attribute__((ext_vector_type(4)));
typedef unsigned int u32;

#define T_ 2048
#define H_ 16
#define C_ 2048

__device__ __forceinline__ void gload_lds16(const f16* g, f16* l) {
  __builtin_amdgcn_global_load_lds((const __attribute__((address_space(1))) u32*)g,
                                   (__attribute__((address_space(3))) u32*)l, 16, 0, 0);
}

// ---------------- cast fp32 -> fp16 (x + 4 weights, one launch) ----------------
__global__ __launch_bounds__(256) void cast_all_kernel(
    const float* __restrict__ x, const float* __restrict__ wq, const float* __restrict__ wk,
    const float* __restrict__ wv, const float* __restrict__ wo,
    f16* __restrict__ xh, f16* __restrict__ wqh, f16* __restrict__ wkh,
    f16* __restrict__ wvh, f16* __restrict__ woh) {
  int b = blockIdx.x;
  const float* src; f16* dst; size_t off;
  if (b < 8192) { src = x; dst = xh; off = (size_t)b * 1024; }
  else {
    int s = (b - 8192) >> 12, bb = (b - 8192) & 4095;
    off = (size_t)bb * 1024;
    if (s == 0) { src = wq; dst = wqh; }
    else if (s == 1) { src = wk; dst = wkh; }
    else if (s == 2) { src = wv; dst = wvh; }
    else { src = wo; dst = woh; }
  }
  size_t i = off + (size_t)threadIdx.x * 4;
  float4 v = *(const float4*)&src[i];
  f16x4 o; o[0] = (f16)v.x; o[1] = (f16)v.y; o[2] = (f16)v.z; o[3] = (f16)v.w;
  *(f16x4*)&dst[i] = o;
}

// ---------------- 128x128 GEMM body (A: MxK row-major, Bm: NxK row-major == B^T) ----------------
template<typename OutT>
__device__ __forceinline__ void gemm128(const f16* __restrict__ A, const f16* __restrict__ Bm,
                                        OutT* __restrict__ Cm, f16* As, f16* Bs,
                                        int brow, int bcol) {
  const int K = 2048, N = 2048;
  const int tid = threadIdx.x, l = tid & 63, w = tid >> 6;
  const int lr = l & 15, lg = l >> 4;
  const int wr = (w >> 1) * 64, wc = (w & 1) * 64;
  const int srow = l >> 2, scol = (l & 3) * 8;
  const f16* gA0 = A + (size_t)(brow + w * 32 + srow) * K + scol;
  const f16* gA1 = gA0 + (size_t)16 * K;
  const f16* gB0 = Bm + (size_t)(bcol + w * 32 + srow) * K + scol;
  const f16* gB1 = gB0 + (size_t)16 * K;
  f16* lA0 = &As[(w * 32 + 0) * 32];
  f16* lA1 = &As[(w * 32 + 16) * 32];
  f16* lB0 = &Bs[(w * 32 + 0) * 32];
  f16* lB1 = &Bs[(w * 32 + 16) * 32];
  f32x4 acc[4][4] = {};
  for (int kt = 0; kt < K; kt += 32) {
    gload_lds16(gA0 + kt, lA0);
    gload_lds16(gA1 + kt, lA1);
    gload_lds16(gB0 + kt, lB0);
    gload_lds16(gB1 + kt, lB1);
    __syncthreads();
    f16x8 af[4], bf[4];
#pragma unroll
    for (int m = 0; m < 4; ++m) af[m] = *(const f16x8*)&As[(wr + m * 16 + lr) * 32 + lg * 8];
#pragma unroll
    for (int n = 0; n < 4; ++n) bf[n] = *(const f16x8*)&Bs[(wc + n * 16 + lr) * 32 + lg * 8];
#pragma unroll
    for (int m = 0; m < 4; ++m)
#pragma unroll
      for (int n = 0; n < 4; ++n)
        acc[m][n] = __builtin_amdgcn_mfma_f32_16x16x32_f16(af[m], bf[n], acc[m][n], 0, 0, 0);
    __syncthreads();
  }
#pragma unroll
  for (int m = 0; m < 4; ++m) {
    int row0 = brow + wr + m * 16 + lg * 4;
#pragma unroll
    for (int n = 0; n < 4; ++n) {
      int col = bcol + wc + n * 16 + lr;
#pragma unroll
      for (int j = 0; j < 4; ++j)
        Cm[(size_t)(row0 + j) * N + col] = (OutT)acc[m][n][j];
    }
  }
}

__global__ __launch_bounds__(256) void gemm_qkv_kernel(
    const f16* __restrict__ A, const f16* __restrict__ Wq, const f16* __restrict__ Wk,
    const f16* __restrict__ Wv, f16* __restrict__ Qo, f16* __restrict__ Ko, f16* __restrict__ Vo) {
  __shared__ f16 As[4096], Bs[4096];
  const f16* Bm; f16* Cm;
  if (blockIdx.z == 0) { Bm = Wq; Cm = Qo; }
  else if (blockIdx.z == 1) { Bm = Wk; Cm = Ko; }
  else { Bm = Wv; Cm = Vo; }
  gemm128<f16>(A, Bm, Cm, As, Bs, blockIdx.x * 128, blockIdx.y * 128);
}

__global__ __launch_bounds__(256) void gemm_out_kernel(
    const f16* __restrict__ A, const f16* __restrict__ Wo, float* __restrict__ Cm) {
  __shared__ f16 As[4096], Bs[4096];
  gemm128<float>(A, Wo, Cm, As, Bs, blockIdx.x * 128, blockIdx.y * 128);
}

// ---------------- QK-norm + RoPE (in place, fp16 (b,t,h,d)) ----------------
__global__ __launch_bounds__(256) void normrope_kernel(f16* __restrict__ q,
                                                       const float* __restrict__ qk_scale) {
  int w = threadIdx.x >> 6, l = threadIdx.x & 63;
  int row = blockIdx.x * 4 + w;          // row = (b*T + t)*H + h
  int t = (row >> 4) & (T_ - 1);
  size_t base = (size_t)row * 128;
  float x1 = (float)q[base + l], x2 = (float)q[base + 64 + l];
  float ss = x1 * x1 + x2 * x2;
#pragma unroll
  for (int m = 1; m < 64; m <<= 1) ss += __shfl_xor(ss, m);
  float inv = 1.0f / fmaxf(sqrtf(ss), 1e-12f);
  float sc1 = qk_scale[l] * 45.254833995939045f;       // sqrt(2048)
  float sc2 = qk_scale[l + 64] * 45.254833995939045f;
  float s1 = x1 * inv * sc1, s2 = x2 * inv * sc2;
  // inv_freq = 10000^(-l/64) = exp2(-l * log2(10000)/64)
  float invf = exp2f(-(float)l * 0.20762050593046013f);
  float ang = (float)t * invf;
  float sn, cs; sincosf(ang, &sn, &cs);
  float o1 = s1 * cs + s2 * sn;
  float o2 = -s1 * sn + s2 * cs;
  q[base + l] = (f16)o1;
  q[base + 64 + l] = (f16)o2;
}

// ---------------- causal flash attention ----------------
// Q,K,V fp16 in (b,t,h,d); Y fp16 in (b,t,h*128+d)
__global__ __launch_bounds__(256) void attn_kernel(
    const f16* __restrict__ Q, const f16* __restrict__ K, const f16* __restrict__ V,
    f16* __restrict__ Y) {
  __shared__ f16 Ks[64 * 136];   // [kv][136]
  __shared__ f16 Vt[128 * 72];   // [d][72]  (transposed V)
  __shared__ f16 Ps[4 * 32 * 72];// per-wave [32 q][72]
  const int tid = threadIdx.x, l = tid & 63, w = tid >> 6;
  const int lr = l & 15, lg = l >> 4;
  const int qb = blockIdx.x * 128;
  const int bh = blockIdx.y, b = bh >> 4, h = bh & 15;
  const size_t hb = ((size_t)b * T_ * H_ + h) * 128;   // + t*2048 + d
  const int qw = qb + w * 32;
  f16* Pw = &Ps[w * 32 * 72];

  f16x8 qfr[2][4];
#pragma unroll
  for (int f = 0; f < 2; ++f)
#pragma unroll
    for (int dc = 0; dc < 4; ++dc)
      qfr[f][dc] = *(const f16x8*)&Q[hb + (size_t)(qw + f * 16 + lr) * 2048 + dc * 32 + lg * 8];

  float mreg[2] = {-INFINITY, -INFINITY}, rsum[2] = {0.f, 0.f};
  f32x4 acc[8][2] = {};
  const int ntiles = qb / 64 + 2;

  for (int it = 0; it < ntiles; ++it) {
    const int kv0 = it * 64;
    __syncthreads();
    {   // stage K tile [64][128] -> Ks[64][136]
      int row = tid >> 2, cg = (tid & 3) * 32;
      const f16* src = &K[hb + (size_t)(kv0 + row) * 2048 + cg];
      f16* dst = &Ks[row * 136 + cg];
#pragma unroll
      for (int j = 0; j < 4; ++j) *(f16x8*)(dst + j * 8) = *(const f16x8*)(src + j * 8);
    }
#pragma unroll
    for (int half = 0; half < 2; ++half) {  // stage V transposed -> Vt[128][72]
      int item = tid + half * 256;
      int p2 = item & 31, dg = (item >> 5) * 8;
      int kv = p2 * 2;
      const f16* s0 = &V[hb + (size_t)(kv0 + kv) * 2048 + dg];
      f16x8 r0 = *(const f16x8*)s0;
      f16x8 r1 = *(const f16x8*)(s0 + 2048);
#pragma unroll
      for (int j = 0; j < 8; ++j) {
        union { f16 f2[2]; u32 u; } pk;
        pk.f2[0] = r0[j]; pk.f2[1] = r1[j];
        *(u32*)&Vt[(dg + j) * 72 + kv] = pk.u;
      }
    }
    __syncthreads();
    if (kv0 <= qw + 31) {
#pragma unroll
      for (int f = 0; f < 2; ++f) {
        const int q = qw + f * 16 + lr;
        float p[16];
#pragma unroll
        for (int kt = 0; kt < 4; ++kt) {
          f32x4 s = {0.f, 0.f, 0.f, 0.f};
#pragma unroll
          for (int dc = 0; dc < 4; ++dc) {
            f16x8 kf = *(const f16x8*)&Ks[(kt * 16 + lr) * 136 + dc * 32 + lg * 8];
            s = __builtin_amdgcn_mfma_f32_16x16x32_f16(kf, qfr[f][dc], s, 0, 0, 0);
          }
#pragma unroll
          for (int r = 0; r < 4; ++r) {
            int kv = kv0 + kt * 16 + lg * 4 + r;
            p[kt * 4 + r] = (kv <= q) ? s[r] * 11.313708498984761f : -INFINITY;
          }
        }
        float pm = p[0];
#pragma unroll
        for (int i = 1; i < 16; ++i) pm = fmaxf(pm, p[i]);
        pm = fmaxf(pm, __shfl_xor(pm, 16));
        pm = fmaxf(pm, __shfl_xor(pm, 32));
        float mn = fmaxf(mreg[f], pm);
        float al = __expf(mreg[f] - mn);
        mreg[f] = mn;
        float sum = 0.f;
#pragma unroll
        for (int i = 0; i < 16; ++i) { p[i] = __expf(p[i] - mn); sum += p[i]; }
        sum += __shfl_xor(sum, 16);
        sum += __shfl_xor(sum, 32);
        rsum[f] = rsum[f] * al + sum;
#pragma unroll
        for (int dt = 0; dt < 8; ++dt)
#pragma unroll
          for (int j = 0; j < 4; ++j) acc[dt][f][j] *= al;
#pragma unroll
        for (int kt = 0; kt < 4; ++kt) {
          f16x4 pk;
#pragma unroll
          for (int r = 0; r < 4; ++r) pk[r] = (f16)p[kt * 4 + r];
          *(f16x4*)&Pw[(f * 16 + lr) * 72 + kt * 16 + lg * 4] = pk;
        }
      }
#pragma unroll
      for (int f = 0; f < 2; ++f) {
#pragma unroll
        for (int ks = 0; ks < 2; ++ks) {
          f16x8 pa = *(const f16x8*)&Pw[(f * 16 + lr) * 72 + ks * 32 + lg * 8];
#pragma unroll
          for (int dt = 0; dt < 8; ++dt) {
            f16x8 vf = *(const f16x8*)&Vt[(dt * 16 + lr) * 72 + ks * 32 + lg * 8];
            acc[dt][f] = __builtin_amdgcn_mfma_f32_16x16x32_f16(vf, pa, acc[dt][f], 0, 0, 0);
          }
        }
      }
    }
  }
#pragma unroll
  for (int f = 0; f < 2; ++f) {
    float inv = 1.0f / rsum[f];
    int t = qw + f * 16 + lr;
#pragma unroll
    for (int dt = 0; dt < 8; ++dt) {
      f16x4 pk;
#pragma unroll
      for (int j = 0; j < 4; ++j) pk[j] = (f16)(acc[dt][f][j] * inv);
      size_t off = ((size_t)(b * T_ + t)) * 2048 + h * 128 + dt * 16 + lg * 4;
      *(f16x4*)&Y[off] = pk;
    }
  }
}

// ---------------- host ----------------
extern "C" void kernel_launch(void* const* d_in, const int* in_sizes, int n_in,
                              void* d_out, int out_size, void* d_ws, size_t ws_size,
                              hipStream_t stream) {
  const float* x  = (const float*)d_in[0];
  const float* Wq = (const float*)d_in[1];
  const float* Wk = (const float*)d_in[2];
  const float* Wv = (const float*)d_in[3];
  const float* Wo = (const float*)d_in[4];
  const float* qk_scale = (const float*)d_in[5];
  float* out = (float*)d_out;
  char* ws = (char*)d_ws;

  f16* xh  = (f16*)(ws);                 // 16.8 MB (also reused as yh)
  f16* wqh = (f16*)(ws + 16777216);
  f16* wkh = (f16*)(ws + 25165824);
  f16* wvh = (f16*)(ws + 33554432);
  f16* woh = (f16*)(ws + 41943040);
  f16* qh  = (f16*)(ws + 50331648);
  f16* kh  = (f16*)(ws + 67108864);
  f16* vh  = (f16*)(ws + 83886080);
  f16* yh  = (f16*)(ws + 100663296);

  cast_all_kernel<<<dim3(24576), dim3(256), 0, stream>>>(x, Wq, Wk, Wv, Wo, xh, wqh, wkh, wvh, woh);
  gemm_qkv_kernel<<<dim3(32, 16, 3), dim3(256), 0, stream>>>(xh, wqh, wkh, wvh, qh, kh, vh);
  normrope_kernel<<<dim3(16384), dim3(256), 0, stream>>>(qh, qk_scale);
  normrope_kernel<<<dim3(16384), dim3(256), 0, stream>>>(kh, qk_scale);
  attn_kernel<<<dim3(16, 32), dim3(256), 0, stream>>>(qh, kh, vh, yh);
  gemm_out_kernel<<<dim3(32, 16), dim3(256), 0, stream>>>(yh, woh, out);
}